// Round 1
// baseline (799.273 us; speedup 1.0000x reference)
//
#include <hip/hip_runtime.h>

#define T_STEPS 24
#define BB 64
#define I_DIM 128
#define HH 256
#define RR 64
#define HR 320   // H + R

// ---------------- init: per-(i,j) constants ----------------
__global__ __launch_bounds__(256) void k_init_const(
    const float* __restrict__ alpha, const float* __restrict__ tau_U,
    const float* __restrict__ tau_E, const float* __restrict__ tau_v,
    const float* __restrict__ h2h_w,
    float* __restrict__ ra, float* __restrict__ sU, float* __restrict__ sE,
    float* __restrict__ hi, float* __restrict__ lo, float* __restrict__ sv)
{
    int idx = blockIdx.x * 256 + threadIdx.x;
    if (idx >= HH * HH) return;
    float a = alpha[idx]; a = a > 0.f ? a : 0.f;
    ra[idx] = a;
    sU[idx] = 1.f / (1.f + expf(-tau_U[idx]));
    sE[idx] = 1.f / (1.f + expf(-tau_E[idx]));
    float wv = h2h_w[idx];            // W_hh[i,j] = h2h_w[i*H+j], i<H always here
    float inv = 1.f / (a + 1e-8f);
    float hi_ = 1.0f - wv; hi_ = hi_ > 0.f ? hi_ : 0.f;
    float lo_ = 1.0f + wv; lo_ = lo_ > 0.f ? lo_ : 0.f;
    hi[idx] = hi_ * inv;
    lo[idx] = -lo_ * inv;
    if (idx < HH) sv[idx] = 1.f / (1.f + expf(-tau_v[idx]));
}

// ---------------- init: Wx = LN(x @ x2h_w.T + b) for all T ----------------
__global__ __launch_bounds__(HR) void k_wx(
    const float* __restrict__ x,     // (T*B, I)
    const float* __restrict__ w,     // (HR, I)
    const float* __restrict__ bias,
    const float* __restrict__ g, const float* __restrict__ be,
    float* __restrict__ Wx)          // (T*B, HR)
{
    __shared__ float xs[I_DIM];
    __shared__ float rs[5], rs2[5];
    int row = blockIdx.x;
    int p = threadIdx.x;
    if (p < I_DIM) xs[p] = x[(size_t)row * I_DIM + p];
    __syncthreads();
    const float* wr = w + (size_t)p * I_DIM;
    float acc = bias[p];
    #pragma unroll 8
    for (int k = 0; k < I_DIM; k += 4)
        acc += wr[k]*xs[k] + wr[k+1]*xs[k+1] + wr[k+2]*xs[k+2] + wr[k+3]*xs[k+3];
    float s = acc, s2 = acc * acc;
    int lane = p & 63, wv = p >> 6;
    for (int off = 32; off > 0; off >>= 1) { s += __shfl_down(s, off); s2 += __shfl_down(s2, off); }
    if (lane == 0) { rs[wv] = s; rs2[wv] = s2; }
    __syncthreads();
    float sum = 0.f, sum2 = 0.f;
    #pragma unroll
    for (int q = 0; q < 5; q++) { sum += rs[q]; sum2 += rs2[q]; }
    float mu = sum * (1.f / HR);
    float rstd = rsqrtf(sum2 * (1.f / HR) - mu * mu + 1e-5f);
    Wx[(size_t)row * HR + p] = (acc - mu) * rstd * g[p] + be[p];
}

// ---------------- init: s0 = einsum(ra*dU0, h0) ----------------
__global__ __launch_bounds__(256) void k_s0(
    const float* __restrict__ dU0, const float* __restrict__ h0,
    const float* __restrict__ ra, float* __restrict__ s_out)
{
    int r = blockIdx.x * 4 + (threadIdx.x >> 6);
    int lane = threadIdx.x & 63;
    int b = r >> 8, i = r & 255;
    float4 du = ((const float4*)dU0)[(size_t)r * 64 + lane];
    float4 rv = ((const float4*)ra)[(size_t)i * 64 + lane];
    float4 hv = ((const float4*)h0)[(size_t)b * 64 + lane];
    float acc = rv.x*du.x*hv.x + rv.y*du.y*hv.y + rv.z*du.z*hv.z + rv.w*du.w*hv.w;
    for (int off = 32; off > 0; off >>= 1) acc += __shfl_down(acc, off);
    if (lane == 0) s_out[r] = acc;
}

// ---------------- per-step kernel A: Wh LN, v/nh, mod, nte ----------------
__global__ __launch_bounds__(HR) void k_step_a(
    const float* __restrict__ h_old,   // (B,H)
    const float* __restrict__ v_old,   // (B,H)
    const float* __restrict__ te_old,  // (B,H)
    const float* __restrict__ Wx_t,    // (B,HR)
    const float* __restrict__ s_in,    // (B,H)
    const float* __restrict__ h2h_w,   // (HR,H)
    const float* __restrict__ h2h_b,
    const float* __restrict__ lnh_g, const float* __restrict__ lnh_b,
    const float* __restrict__ sv,      // (H)
    const float* __restrict__ mod2h,   // (H,R)
    float* __restrict__ v_out,         // (B,H)
    float* __restrict__ nh_out,        // (B,H)  = out[t]
    float* __restrict__ nte_out,       // (B,H)
    float* __restrict__ mod_out)       // (B,H)
{
    __shared__ float hs[HH];
    __shared__ float modin[RR];
    __shared__ float rs[5], rs2[5];
    int b = blockIdx.x;
    int p = threadIdx.x;
    if (p < HH) hs[p] = h_old[(size_t)b * HH + p];
    __syncthreads();
    const float* wr = h2h_w + (size_t)p * HH;
    float acc = h2h_b[p];
    #pragma unroll 8
    for (int k = 0; k < HH; k += 4)
        acc += wr[k]*hs[k] + wr[k+1]*hs[k+1] + wr[k+2]*hs[k+2] + wr[k+3]*hs[k+3];
    float s = acc, s2 = acc * acc;
    int lane = p & 63, wv = p >> 6;
    for (int off = 32; off > 0; off >>= 1) { s += __shfl_down(s, off); s2 += __shfl_down(s2, off); }
    if (lane == 0) { rs[wv] = s; rs2[wv] = s2; }
    __syncthreads();
    float sum = 0.f, sum2 = 0.f;
    #pragma unroll
    for (int q = 0; q < 5; q++) { sum += rs[q]; sum2 += rs2[q]; }
    float mu = sum * (1.f / HR);
    float rstd = rsqrtf(sum2 * (1.f / HR) - mu * mu + 1e-5f);
    float wh = (acc - mu) * rstd * lnh_g[p] + lnh_b[p];
    float wx = Wx_t[(size_t)b * HR + p];
    if (p >= HH) {
        float m = wx + wh;
        modin[p - HH] = m > 0.f ? m : 0.f;
    } else {
        float dv = wx + wh + s_in[(size_t)b * HH + p];
        float svp = sv[p];
        float v = (1.f - svp) * v_old[(size_t)b * HH + p] + svp * dv;
        v_out[(size_t)b * HH + p] = v;
        float nh = v > 0.f ? v : 0.f;
        nh_out[(size_t)b * HH + p] = nh;
        nte_out[(size_t)b * HH + p] = (1.f - svp) * te_old[(size_t)b * HH + p] + svp * hs[p];
    }
    __syncthreads();
    if (p < HH) {
        const float* m2 = mod2h + (size_t)p * RR;
        float mm = 0.f;
        #pragma unroll 8
        for (int r = 0; r < RR; r += 4)
            mm += m2[r]*modin[r] + m2[r+1]*modin[r+1] + m2[r+2]*modin[r+2] + m2[r+3]*modin[r+3];
        mod_out[(size_t)b * HH + p] = mm;
    }
}

// ---------------- per-step kernel B: tE/dU update + fused einsum ----------------
__global__ __launch_bounds__(256) void k_step_b(
    const float* __restrict__ dU_old, float* __restrict__ dU_new,
    const float* __restrict__ tE_old, float* __restrict__ tE_new,
    const float* __restrict__ nh,     // (B,H)
    const float* __restrict__ h_old,  // (B,H)
    const float* __restrict__ te_old, // (B,H)
    const float* __restrict__ nte,    // (B,H)
    const float* __restrict__ mod,    // (B,H)
    const float* __restrict__ ra, const float* __restrict__ sU,
    const float* __restrict__ sE, const float* __restrict__ hi,
    const float* __restrict__ lo,
    float* __restrict__ s_out)        // (B,H)
{
    int r = blockIdx.x * 4 + (threadIdx.x >> 6);   // row = b*H + i
    int lane = threadIdx.x & 63;
    int b = r >> 8, i = r & 255;
    size_t rowv = (size_t)r * 64 + lane;           // float4 units
    size_t cv   = (size_t)i * 64 + lane;
    size_t bv   = (size_t)b * 64 + lane;
    float4 du  = ((const float4*)dU_old)[rowv];
    float4 tE  = ((const float4*)tE_old)[rowv];
    float4 raV = ((const float4*)ra)[cv];
    float4 sUV = ((const float4*)sU)[cv];
    float4 sEV = ((const float4*)sE)[cv];
    float4 hiV = ((const float4*)hi)[cv];
    float4 loV = ((const float4*)lo)[cv];
    float4 teV = ((const float4*)te_old)[bv];
    float4 hV  = ((const float4*)h_old)[bv];
    float4 nhJ = ((const float4*)nh)[bv];
    float nhi  = nh[(size_t)b * HH + i];
    float ntei = nte[(size_t)b * HH + i];
    float modi = mod[(size_t)b * HH + i];

    float4 ntE, ndu;
    float acc = 0.f;
#define COMPONENT(c)                                                        \
    {                                                                       \
        float e = (1.f - sEV.c) * tE.c + sEV.c * (nhi * teV.c - ntei * hV.c); \
        float d = (1.f - sUV.c) * du.c + sUV.c * modi * e;                  \
        d = fminf(d, hiV.c); d = fmaxf(d, loV.c);                           \
        ntE.c = e; ndu.c = d;                                               \
        acc += raV.c * d * nhJ.c;                                           \
    }
    COMPONENT(x) COMPONENT(y) COMPONENT(z) COMPONENT(w)
#undef COMPONENT
    ((float4*)tE_new)[rowv] = ntE;
    ((float4*)dU_new)[rowv] = ndu;
    for (int off = 32; off > 0; off >>= 1) acc += __shfl_down(acc, off);
    if (lane == 0) s_out[r] = acc;
}

extern "C" void kernel_launch(void* const* d_in, const int* in_sizes, int n_in,
                              void* d_out, int out_size, void* d_ws, size_t ws_size,
                              hipStream_t stream)
{
    const float* x     = (const float*)d_in[0];
    const float* h0    = (const float*)d_in[1];
    const float* v0    = (const float*)d_in[2];
    const float* dU0   = (const float*)d_in[3];
    const float* te0   = (const float*)d_in[4];
    const float* tE0   = (const float*)d_in[5];
    const float* x2h_w = (const float*)d_in[6];
    const float* x2h_b = (const float*)d_in[7];
    const float* h2h_w = (const float*)d_in[8];
    const float* h2h_b = (const float*)d_in[9];
    const float* lnx_g = (const float*)d_in[10];
    const float* lnx_b = (const float*)d_in[11];
    const float* lnh_g = (const float*)d_in[12];
    const float* lnh_b = (const float*)d_in[13];
    const float* alpha = (const float*)d_in[14];
    const float* mod2h = (const float*)d_in[15];
    const float* tau_v = (const float*)d_in[16];
    const float* tau_U = (const float*)d_in[17];
    const float* tau_E = (const float*)d_in[18];

    float* out  = (float*)d_out;
    float* o_v  = out;                 // (B,H)
    float* o_h  = out + 16384;         // (B,H)
    float* o_dU = out + 32768;         // (B,H,H)
    float* o_te = out + 4227072;       // (B,H)
    float* o_tE = out + 4243456;       // (B,H,H)
    float* o_out= out + 8437760;       // (T,B,H)

    float* w = (float*)d_ws;
    float* Wx  = w;  w += (size_t)T_STEPS * BB * HR;  // 491520
    float* ra  = w;  w += HH * HH;
    float* sU  = w;  w += HH * HH;
    float* sE  = w;  w += HH * HH;
    float* hi  = w;  w += HH * HH;
    float* lo  = w;  w += HH * HH;
    float* sv  = w;  w += 256;
    float* s_buf = w; w += BB * HH;
    float* modb  = w; w += BB * HH;
    float* nteb0 = w; w += BB * HH;
    float* nteb1 = w; w += BB * HH;
    float* nteb[2] = { nteb0, nteb1 };

    k_init_const<<<256, 256, 0, stream>>>(alpha, tau_U, tau_E, tau_v, h2h_w,
                                          ra, sU, sE, hi, lo, sv);
    k_wx<<<T_STEPS * BB, HR, 0, stream>>>(x, x2h_w, x2h_b, lnx_g, lnx_b, Wx);
    k_s0<<<4096, 256, 0, stream>>>(dU0, h0, ra, s_buf);

    for (int t = 0; t < T_STEPS; t++) {
        const float* h_old  = (t == 0) ? h0  : o_out + (size_t)(t - 1) * BB * HH;
        const float* v_old  = (t == 0) ? v0  : o_v;
        const float* te_oldp= (t == 0) ? te0 : nteb[(t + 1) & 1];
        const float* dUo    = (t == 0) ? dU0 : o_dU;
        const float* tEo    = (t == 0) ? tE0 : o_tE;
        float* nh = o_out + (size_t)t * BB * HH;
        k_step_a<<<BB, HR, 0, stream>>>(h_old, v_old, te_oldp,
                                        Wx + (size_t)t * BB * HR, s_buf,
                                        h2h_w, h2h_b, lnh_g, lnh_b, sv, mod2h,
                                        o_v, nh, nteb[t & 1], modb);
        k_step_b<<<4096, 256, 0, stream>>>(dUo, o_dU, tEo, o_tE, nh, h_old,
                                           te_oldp, nteb[t & 1], modb,
                                           ra, sU, sE, hi, lo, s_buf);
    }
    hipMemcpyAsync(o_h,  o_out + (size_t)(T_STEPS - 1) * BB * HH, (size_t)BB * HH * 4,
                   hipMemcpyDeviceToDevice, stream);
    hipMemcpyAsync(o_te, nteb[(T_STEPS - 1) & 1], (size_t)BB * HH * 4,
                   hipMemcpyDeviceToDevice, stream);
}